// Round 10
// baseline (6363.715 us; speedup 1.0000x reference)
//
#include <hip/hip_runtime.h>

// ---------------- problem constants ----------------
#define S_LEN 512
#define HID   512
#define IN_D  64
#define GATES 2048            // 4*HID
#define K0    576             // IN_D + HID
#define K1    1024            // HID + HID
#define KP0   578             // padded LDS stride (dwords % 32 == 1 -> conflict-free B reads)
#define KP1   1026
#define CLUSTERS 4
#define WGS   64              // workgroups per cluster
#define BPC   16              // batch rows per cluster
#define NBLOCKS 256
#define NTHREADS 256
#define NEED_W 32u            // producers per counter word (128 waves / 4 words)

typedef _Float16 f16;
typedef _Float16 f16x8 __attribute__((ext_vector_type(8)));
typedef float    f32x4 __attribute__((ext_vector_type(4)));

// ---------------- LDS layout (dynamic) ----------------
#define LDS_W0_OFF  0
#define LDS_W1_OFF  (32 * KP0 * 2)                    // 36992
#define LDS_STG_OFF (LDS_W1_OFF + 32 * KP1 * 2)      // 102656
#define LDS_TOTAL   (LDS_STG_OFF + 4 * 16 * 17 * 4)  // 107008 bytes

// ---------------- workspace layout ----------------
// [0 .. 64K): per-cluster 4-WORD step counters (ROUND-10 DELTA).
//   cluster c at ws + c*16384:
//     f0cnt = u32[512][4] (8 KB), f1cnt = u32[512][4] at +8192.
//   Producer wave wid (0..127) bumps word (wid & 3) of its step:
//   "h ready at t" <=> all 4 words of cnt[t] == 32. Publish-side RMW
//   serialization drops 128 -> 32 per word (round-8/9 counters showed the
//   single-word design put ~4-10k cy of atomic queueing on the critical path).
// [64K .. ): versioned h slots (UNCHANGED):
//   (cl*2+layer)*Wn + (t & wmask), 32 KB each (hi plane 16 KB, lo plane 16 KB)
#define WS_FLAG_BYTES 65536
#define SLOT_BYTES    32768

#define RELEASE_DRAIN() asm volatile("s_waitcnt vmcnt(0) lgkmcnt(0)" ::: "memory")
#define MFMA(a,b,c) __builtin_amdgcn_mfma_f32_16x16x32_f16((a),(b),(c),0,0,0)

__device__ __forceinline__ float sigf(float v) {
  v = fminf(fmaxf(v, -30.f), 30.f);
  return 1.f / (1.f + __expf(-v));
}
__device__ __forceinline__ float tanh_f(float v) {
  v = fminf(fmaxf(v, -15.f), 15.f);
  float e = __expf(2.f * v);
  return (e - 1.f) / (e + 1.f);
}

__device__ __forceinline__ bool cnt4_ok(unsigned long long a, unsigned long long b) {
  return ((unsigned)a >= NEED_W) && ((unsigned)(a >> 32) >= NEED_W) &&
         ((unsigned)b >= NEED_W) && ((unsigned)(b >> 32) >= NEED_W);
}

// poll one 4-word counter group (two u64 loads of one 16B beat).
// budget bail-out: protocol failure finishes fast with wrong numbers (loud).
__device__ __forceinline__ void wait_cnt4(const unsigned* p, int& budget) {
  const unsigned long long* q = (const unsigned long long*)p;
  for (;;) {
    unsigned long long a = __hip_atomic_load(q,     __ATOMIC_RELAXED, __HIP_MEMORY_SCOPE_AGENT);
    unsigned long long b = __hip_atomic_load(q + 1, __ATOMIC_RELAXED, __HIP_MEMORY_SCOPE_AGENT);
    if (cnt4_ok(a, b)) break;
    if (--budget < 0) break;
    __builtin_amdgcn_s_sleep(1);
  }
  asm volatile("" ::: "memory");   // compiler acquire: keep data loads after the poll
}

// poll two counter groups concurrently (merged detect latency).
__device__ __forceinline__ void wait_cnt4_both(const unsigned* p0, const unsigned* p1, int& budget) {
  const unsigned long long* q0 = (const unsigned long long*)p0;
  const unsigned long long* q1 = (const unsigned long long*)p1;
  bool d0 = false, d1 = false;
  for (;;) {
    if (!d0) {
      unsigned long long a = __hip_atomic_load(q0,     __ATOMIC_RELAXED, __HIP_MEMORY_SCOPE_AGENT);
      unsigned long long b = __hip_atomic_load(q0 + 1, __ATOMIC_RELAXED, __HIP_MEMORY_SCOPE_AGENT);
      d0 = cnt4_ok(a, b);
    }
    if (!d1) {
      unsigned long long a = __hip_atomic_load(q1,     __ATOMIC_RELAXED, __HIP_MEMORY_SCOPE_AGENT);
      unsigned long long b = __hip_atomic_load(q1 + 1, __ATOMIC_RELAXED, __HIP_MEMORY_SCOPE_AGENT);
      d1 = cnt4_ok(a, b);
    }
    if (d0 && d1) break;
    if (--budget < 0) break;
    __builtin_amdgcn_s_sleep(1);
  }
  asm volatile("" ::: "memory");
}

extern "C" __global__ void __launch_bounds__(NTHREADS, 1)
lstm_persist(const float* __restrict__ x,  const float* __restrict__ W0,
             const float* __restrict__ b0, const float* __restrict__ W1,
             const float* __restrict__ b1, const float* __restrict__ Wfc,
             const float* __restrict__ bfc, float* __restrict__ out,
             unsigned char* __restrict__ ws, int Wn, int wmask, int fimask, int slack)
{
  extern __shared__ char lds[];
  f16*   w0l     = (f16*)(lds + LDS_W0_OFF);
  f16*   w1l     = (f16*)(lds + LDS_W1_OFF);
  float* stgbase = (float*)(lds + LDS_STG_OFF);

  const int tid   = threadIdx.x;
  const int wg    = blockIdx.x & (WGS - 1);
  const int cl    = blockIdx.x / WGS;
  const int wave  = tid >> 6;
  const int lane  = tid & 63;
  const int hbase = wg * 8;

  // ---- one-time: gather + transpose this WG's weight columns into LDS (fp16) ----
  {
    const int nl = tid & 31;
    const int wtile = nl >> 4, wi = nl & 15, g = wi >> 2, jj = wi & 3;
    const int col = g * HID + hbase + wtile * 4 + jj;
    for (int k = tid >> 5; k < K0; k += 8)
      w0l[nl * KP0 + k] = (f16)W0[(size_t)k * GATES + col];
    for (int k = tid >> 5; k < K1; k += 8)
      w1l[nl * KP1 + k] = (f16)W1[(size_t)k * GATES + col];
  }
  __syncthreads();   // last block-wide sync; waves run independently below

  // ---- per-wave constants ----
  const int layer = wave >> 1;
  const int tile  = wave & 1;
  const int cb    = hbase + tile * 4;
  const int erow  = lane >> 2;
  const int ehc   = lane & 3;
  const int hcol  = cb + ehc;
  const float* bsrc = layer ? b1 : b0;
  const float bg0 = bsrc[0 * HID + hcol];
  const float bg1 = bsrc[1 * HID + hcol];
  const float bg2 = bsrc[2 * HID + hcol];
  const float bg3 = bsrc[3 * HID + hcol];
  float cstate = 0.f;
  float* stg = stgbase + wave * (16 * 17);

  const int fm  = lane & 15;
  const int q8  = (lane >> 4) * 8;
  const int brow = cl * BPC + fm;
  const int wid  = wg * 2 + tile;          // producer wave id 0..127
  const int word = wid & 3;                // counter word this wave bumps

  unsigned char* hby = ws + WS_FLAG_BYTES;
  unsigned int* f0cnt = (unsigned int*)(ws + (size_t)cl * 16384);
  unsigned int* f1cnt = (unsigned int*)(ws + (size_t)cl * 16384 + 8192);
  int budget = 1 << 20;

  auto slotp = [&](int lyr, int t, int hl) -> f16* {
    return (f16*)(hby + ((size_t)((cl * 2 + lyr) * Wn + (t & wmask)) << 15) + (hl << 14));
  };

  // epilogue: acc -> gates -> (h, cstate) -> versioned slot store
  auto do_epilogue = [&](f32x4 acc, int t) {
    #pragma unroll
    for (int r = 0; r < 4; ++r)
      stg[((lane >> 4) * 4 + r) * 17 + fm] = acc[r];
    float iv = stg[erow * 17 + 0 + ehc]  + bg0;
    float fv = stg[erow * 17 + 4 + ehc]  + bg1;
    float gv = stg[erow * 17 + 8 + ehc]  + bg2;
    float ov = stg[erow * 17 + 12 + ehc] + bg3;
    float ig = sigf(iv), fg = sigf(fv), gg = tanh_f(gv), og = sigf(ov);
    cstate = fg * cstate + ig * gg;
    float h = og * tanh_f(cstate);

    const int src0 = fm * 4 + ((lane >> 4) & 1) * 2;
    float ha = __shfl(h, src0, 64);
    float hb = __shfl(h, src0 + 1, 64);
    if (lane < 32) {
      const int wrow = lane & 15, wpair = lane >> 4;
      f16* phi = slotp(layer, t, 0);
      f16* plo = slotp(layer, t, 1);
      f16 hah = (f16)ha; f16 hal = (f16)(ha - (float)hah);
      f16 hbh = (f16)hb; f16 hbl = (f16)(hb - (float)hbh);
      unsigned int hw = (unsigned int)__builtin_bit_cast(unsigned short, hah) |
                        ((unsigned int)__builtin_bit_cast(unsigned short, hbh) << 16);
      unsigned int lw = (unsigned int)__builtin_bit_cast(unsigned short, hal) |
                        ((unsigned int)__builtin_bit_cast(unsigned short, hbl) << 16);
      const int coff = wrow * HID + cb + wpair * 2;
      __hip_atomic_store((unsigned int*)(phi + coff), hw, __ATOMIC_RELAXED, __HIP_MEMORY_SCOPE_AGENT);
      __hip_atomic_store((unsigned int*)(plo + coff), lw, __ATOMIC_RELAXED, __HIP_MEMORY_SCOPE_AGENT);
    }
    RELEASE_DRAIN();   // h stores ack'd at coherence point before the count bump
  };

  if (layer == 0) {
    for (int t = 0; t < S_LEN; ++t) {
      if (t && (t & fimask) == 0)
        __builtin_amdgcn_fence(__ATOMIC_ACQUIRE, "agent");  // slot-reuse invalidate (every W/2)
      f32x4 acc = {0.f, 0.f, 0.f, 0.f};
      // x part first: independent of the recurrence
      const float* xr = x + ((size_t)brow * S_LEN + t) * IN_D + q8;
      #pragma unroll
      for (int kb = 0; kb < 2; ++kb) {
        f32x4 xa = *(const f32x4*)(xr + kb * 32);
        f32x4 xb = *(const f32x4*)(xr + kb * 32 + 4);
        f16x8 a = { (f16)xa[0], (f16)xa[1], (f16)xa[2], (f16)xa[3],
                    (f16)xb[0], (f16)xb[1], (f16)xb[2], (f16)xb[3] };
        f16x8 bf = *(const f16x8*)(w0l + (tile * 16 + fm) * KP0 + kb * 32 + q8);
        acc = MFMA(a, bf, acc);
      }
      if (t) {
        if (t > slack)
          wait_cnt4_both(f0cnt + (t - 1) * 4, f1cnt + (t - slack - 1) * 4, budget);
        else
          wait_cnt4(f0cnt + (t - 1) * 4, budget);
        const f16* hpi = slotp(0, t - 1, 0) + fm * HID + q8;
        const f16* hpl = slotp(0, t - 1, 1) + fm * HID + q8;
        f16x8 ah[16], al[16];
        #pragma unroll
        for (int kb = 0; kb < 16; ++kb) {
          ah[kb] = *(const f16x8*)(hpi + kb * 32);
          al[kb] = *(const f16x8*)(hpl + kb * 32);
        }
        f32x4 acl = {0.f, 0.f, 0.f, 0.f};
        #pragma unroll
        for (int kb = 0; kb < 16; ++kb) {
          f16x8 bf = *(const f16x8*)(w0l + (tile * 16 + fm) * KP0 + IN_D + kb * 32 + q8);
          acc = MFMA(ah[kb], bf, acc);
          acl = MFMA(al[kb], bf, acl);
        }
        acc = acc + acl;
      }
      do_epilogue(acc, t);
      if (lane == 0) atomicAdd(f0cnt + t * 4 + word, 1u);       // device-scope (G12)
    }
  } else {
    for (int t = 0; t < S_LEN; ++t) {
      if (t && (t & fimask) == 0)
        __builtin_amdgcn_fence(__ATOMIC_ACQUIRE, "agent");
      // ROUND-10 DELTA: fused phases — wait both deps, load both batches,
      // then run 4 independent MFMA chains (one latency exposure, not two).
      if (t)
        wait_cnt4_both(f0cnt + t * 4, f1cnt + (t - 1) * 4, budget);
      else
        wait_cnt4(f0cnt, budget);

      f32x4 a0 = {0.f,0.f,0.f,0.f}, a1 = {0.f,0.f,0.f,0.f};
      f32x4 a2 = {0.f,0.f,0.f,0.f}, a3 = {0.f,0.f,0.f,0.f};
      {
        const f16* h0i = slotp(0, t, 0) + fm * HID + q8;
        const f16* h0l = slotp(0, t, 1) + fm * HID + q8;
        if (t) {
          const f16* h1i = slotp(1, t - 1, 0) + fm * HID + q8;
          const f16* h1l = slotp(1, t - 1, 1) + fm * HID + q8;
          f16x8 ah0[16], al0[16], ah1[16], al1[16];
          #pragma unroll
          for (int kb = 0; kb < 16; ++kb) {
            ah0[kb] = *(const f16x8*)(h0i + kb * 32);
            al0[kb] = *(const f16x8*)(h0l + kb * 32);
            ah1[kb] = *(const f16x8*)(h1i + kb * 32);
            al1[kb] = *(const f16x8*)(h1l + kb * 32);
          }
          #pragma unroll
          for (int kb = 0; kb < 16; ++kb) {
            f16x8 bf0 = *(const f16x8*)(w1l + (tile * 16 + fm) * KP1 + kb * 32 + q8);
            f16x8 bf1 = *(const f16x8*)(w1l + (tile * 16 + fm) * KP1 + HID + kb * 32 + q8);
            a0 = MFMA(ah0[kb], bf0, a0);
            a1 = MFMA(al0[kb], bf0, a1);
            a2 = MFMA(ah1[kb], bf1, a2);
            a3 = MFMA(al1[kb], bf1, a3);
          }
        } else {
          f16x8 ah0[16], al0[16];
          #pragma unroll
          for (int kb = 0; kb < 16; ++kb) {
            ah0[kb] = *(const f16x8*)(h0i + kb * 32);
            al0[kb] = *(const f16x8*)(h0l + kb * 32);
          }
          #pragma unroll
          for (int kb = 0; kb < 16; ++kb) {
            f16x8 bf0 = *(const f16x8*)(w1l + (tile * 16 + fm) * KP1 + kb * 32 + q8);
            a0 = MFMA(ah0[kb], bf0, a0);
            a1 = MFMA(al0[kb], bf0, a1);
          }
        }
      }
      f32x4 acc = (a0 + a1) + (a2 + a3);
      do_epilogue(acc, t);
      if (lane == 0) atomicAdd(f1cnt + t * 4 + word, 1u);
    }
  }

  // ---- output head: WG0 of each cluster reads h1(511) ----
  if (wg == 0) {
    wait_cnt4(f1cnt + (S_LEN - 1) * 4, budget);
    __builtin_amdgcn_fence(__ATOMIC_ACQUIRE, "agent");
    const f16* h1i = slotp(1, S_LEN - 1, 0);
    const f16* h1l = slotp(1, S_LEN - 1, 1);
    #pragma unroll
    for (int rr = 0; rr < 4; ++rr) {
      const int r = wave * 4 + rr;
      float sum = 0.f;
      for (int k = lane; k < HID; k += 64) {
        float hv = (float)h1i[r * HID + k] + (float)h1l[r * HID + k];
        sum += hv * Wfc[k];
      }
      #pragma unroll
      for (int off = 32; off > 0; off >>= 1)
        sum += __shfl_down(sum, off, 64);
      if (lane == 0) out[cl * BPC + r] = sum + bfc[0];
    }
  }
}

extern "C" void kernel_launch(void* const* d_in, const int* in_sizes, int n_in,
                              void* d_out, int out_size, void* d_ws, size_t ws_size,
                              hipStream_t stream) {
  const float* x   = (const float*)d_in[0];
  const float* W0  = (const float*)d_in[1];
  const float* b0  = (const float*)d_in[2];
  const float* W1  = (const float*)d_in[3];
  const float* b1  = (const float*)d_in[4];
  const float* Wfc = (const float*)d_in[5];
  const float* bfc = (const float*)d_in[6];
  float* out = (float*)d_out;
  unsigned char* ws = (unsigned char*)d_ws;

  (void)in_sizes; (void)n_in; (void)out_size;

  // window size from available workspace (cap 64 slots = 16.8 MB)
  int Wn = 2;
  while (Wn < 64 &&
         WS_FLAG_BYTES + (size_t)(Wn * 2) * (CLUSTERS * 2 * SLOT_BYTES) <= ws_size)
    Wn *= 2;
  int wmask  = Wn - 1;
  int fimask = (Wn >= 4) ? (Wn / 2 - 1) : 0;  // acquire-fence every Wn/2 steps
  int slack  = Wn - 2;

  hipFuncSetAttribute((const void*)lstm_persist,
                      hipFuncAttributeMaxDynamicSharedMemorySize, LDS_TOTAL);

  // zero the counter region each call (h slots are written before read)
  hipMemsetAsync(ws, 0, WS_FLAG_BYTES, stream);

  void* args[] = { &x, &W0, &b0, &W1, &b1, &Wfc, &bfc, &out, &ws,
                   &Wn, &wmask, &fimask, &slack };
  hipLaunchCooperativeKernel((void*)lstm_persist, dim3(NBLOCKS), dim3(NTHREADS),
                             args, LDS_TOTAL, stream);
}

// Round 11
// 4714.331 us; speedup vs baseline: 1.3499x; 1.3499x over previous
//
#include <hip/hip_runtime.h>

// ---------------- problem constants ----------------
#define S_LEN 512
#define HID   512
#define IN_D  64
#define GATES 2048            // 4*HID
#define K0    576             // IN_D + HID
#define K1    1024            // HID + HID
#define KP0   578             // padded LDS stride (dwords % 32 == 1 -> conflict-free B reads)
#define KP1   1026
#define CLUSTERS 4
#define WGS   64              // workgroups per cluster
#define BPC   16              // batch rows per cluster
#define NBLOCKS 256
#define NTHREADS 256
#define NEED_W 32u            // producers per counter word (128 waves / 4 words)

typedef _Float16 f16;
typedef _Float16 f16x8 __attribute__((ext_vector_type(8)));
typedef float    f32x4 __attribute__((ext_vector_type(4)));

// ---------------- LDS layout (dynamic) ----------------
#define LDS_W0_OFF  0
#define LDS_W1_OFF  (32 * KP0 * 2)                    // 36992
#define LDS_STG_OFF (LDS_W1_OFF + 32 * KP1 * 2)      // 102656
#define LDS_TOTAL   (LDS_STG_OFF + 4 * 16 * 17 * 4)  // 107008 bytes

// ---------------- workspace layout ----------------
// [0 .. 64K): per-cluster 4-LINE step counters (ROUND-11 DELTA).
//   cluster c at ws + c*16384:
//     f0cnt: 4 word-arrays u32[512], word w at +w*2048   (8 KB total)
//     f1cnt: same, at +8192.
//   Producer wave wid (0..127) bumps word (wid & 3) of its step:
//   "h ready at t" <=> all 4 words of cnt[.][t] == 32. The 4 words sit on
//   4 DIFFERENT cache lines (2 KB apart) -> publish-side RMW serialization
//   drops 128-per-line to 32-per-line x 4 parallel streams. (Round 10 put
//   the 4 words in ONE 16B group = same line = null; its regression came
//   from the bundled phase-fusion, reverted here.)
// [64K .. ): versioned h slots (UNCHANGED):
//   (cl*2+layer)*Wn + (t & wmask), 32 KB each (hi plane 16 KB, lo plane 16 KB)
#define WS_FLAG_BYTES 65536
#define SLOT_BYTES    32768

#define RELEASE_DRAIN() asm volatile("s_waitcnt vmcnt(0) lgkmcnt(0)" ::: "memory")
#define MFMA(a,b,c) __builtin_amdgcn_mfma_f32_16x16x32_f16((a),(b),(c),0,0,0)

__device__ __forceinline__ float sigf(float v) {
  v = fminf(fmaxf(v, -30.f), 30.f);
  return 1.f / (1.f + __expf(-v));
}
__device__ __forceinline__ float tanh_f(float v) {
  v = fminf(fmaxf(v, -15.f), 15.f);
  float e = __expf(2.f * v);
  return (e - 1.f) / (e + 1.f);
}

// poll one step's 4 spread counter words (4 concurrent loads, 4 lines).
// budget bail-out: protocol failure finishes fast with wrong numbers (loud).
__device__ __forceinline__ void wait4(const unsigned* arr, int t, int& budget) {
  const unsigned* p0 = arr + t;
  const unsigned* p1 = arr + 512 + t;
  const unsigned* p2 = arr + 1024 + t;
  const unsigned* p3 = arr + 1536 + t;
  for (;;) {
    unsigned a = __hip_atomic_load(p0, __ATOMIC_RELAXED, __HIP_MEMORY_SCOPE_AGENT);
    unsigned b = __hip_atomic_load(p1, __ATOMIC_RELAXED, __HIP_MEMORY_SCOPE_AGENT);
    unsigned c = __hip_atomic_load(p2, __ATOMIC_RELAXED, __HIP_MEMORY_SCOPE_AGENT);
    unsigned d = __hip_atomic_load(p3, __ATOMIC_RELAXED, __HIP_MEMORY_SCOPE_AGENT);
    if (a >= NEED_W && b >= NEED_W && c >= NEED_W && d >= NEED_W) break;
    if (--budget < 0) break;
    __builtin_amdgcn_s_sleep(1);
  }
  asm volatile("" ::: "memory");   // compiler acquire: keep data loads after the poll
}

extern "C" __global__ void __launch_bounds__(NTHREADS, 1)
lstm_persist(const float* __restrict__ x,  const float* __restrict__ W0,
             const float* __restrict__ b0, const float* __restrict__ W1,
             const float* __restrict__ b1, const float* __restrict__ Wfc,
             const float* __restrict__ bfc, float* __restrict__ out,
             unsigned char* __restrict__ ws, int Wn, int wmask, int fimask, int slack)
{
  extern __shared__ char lds[];
  f16*   w0l     = (f16*)(lds + LDS_W0_OFF);
  f16*   w1l     = (f16*)(lds + LDS_W1_OFF);
  float* stgbase = (float*)(lds + LDS_STG_OFF);

  const int tid   = threadIdx.x;
  const int wg    = blockIdx.x & (WGS - 1);
  const int cl    = blockIdx.x / WGS;
  const int wave  = tid >> 6;
  const int lane  = tid & 63;
  const int hbase = wg * 8;

  // ---- one-time: gather + transpose this WG's weight columns into LDS (fp16) ----
  {
    const int nl = tid & 31;
    const int wtile = nl >> 4, wi = nl & 15, g = wi >> 2, jj = wi & 3;
    const int col = g * HID + hbase + wtile * 4 + jj;
    for (int k = tid >> 5; k < K0; k += 8)
      w0l[nl * KP0 + k] = (f16)W0[(size_t)k * GATES + col];
    for (int k = tid >> 5; k < K1; k += 8)
      w1l[nl * KP1 + k] = (f16)W1[(size_t)k * GATES + col];
  }
  __syncthreads();   // last block-wide sync; waves run independently below

  // ---- per-wave constants ----
  const int layer = wave >> 1;
  const int tile  = wave & 1;
  const int cb    = hbase + tile * 4;
  const int erow  = lane >> 2;
  const int ehc   = lane & 3;
  const int hcol  = cb + ehc;
  const float* bsrc = layer ? b1 : b0;
  const float bg0 = bsrc[0 * HID + hcol];
  const float bg1 = bsrc[1 * HID + hcol];
  const float bg2 = bsrc[2 * HID + hcol];
  const float bg3 = bsrc[3 * HID + hcol];
  float cstate = 0.f;
  float* stg = stgbase + wave * (16 * 17);

  const int fm  = lane & 15;
  const int q8  = (lane >> 4) * 8;
  const int brow = cl * BPC + fm;
  const int wid  = wg * 2 + tile;          // producer wave id 0..127
  const int word = wid & 3;                // which spread line this wave bumps

  unsigned char* hby = ws + WS_FLAG_BYTES;
  unsigned int* f0cnt = (unsigned int*)(ws + (size_t)cl * 16384);
  unsigned int* f1cnt = (unsigned int*)(ws + (size_t)cl * 16384 + 8192);
  int budget = 1 << 20;

  auto slotp = [&](int lyr, int t, int hl) -> f16* {
    return (f16*)(hby + ((size_t)((cl * 2 + lyr) * Wn + (t & wmask)) << 15) + (hl << 14));
  };

  // epilogue: acc -> gates -> (h, cstate) -> versioned slot store
  auto do_epilogue = [&](f32x4 acc, int t) {
    #pragma unroll
    for (int r = 0; r < 4; ++r)
      stg[((lane >> 4) * 4 + r) * 17 + fm] = acc[r];
    float iv = stg[erow * 17 + 0 + ehc]  + bg0;
    float fv = stg[erow * 17 + 4 + ehc]  + bg1;
    float gv = stg[erow * 17 + 8 + ehc]  + bg2;
    float ov = stg[erow * 17 + 12 + ehc] + bg3;
    float ig = sigf(iv), fg = sigf(fv), gg = tanh_f(gv), og = sigf(ov);
    cstate = fg * cstate + ig * gg;
    float h = og * tanh_f(cstate);

    const int src0 = fm * 4 + ((lane >> 4) & 1) * 2;
    float ha = __shfl(h, src0, 64);
    float hb = __shfl(h, src0 + 1, 64);
    if (lane < 32) {
      const int wrow = lane & 15, wpair = lane >> 4;
      f16* phi = slotp(layer, t, 0);
      f16* plo = slotp(layer, t, 1);
      f16 hah = (f16)ha; f16 hal = (f16)(ha - (float)hah);
      f16 hbh = (f16)hb; f16 hbl = (f16)(hb - (float)hbh);
      unsigned int hw = (unsigned int)__builtin_bit_cast(unsigned short, hah) |
                        ((unsigned int)__builtin_bit_cast(unsigned short, hbh) << 16);
      unsigned int lw = (unsigned int)__builtin_bit_cast(unsigned short, hal) |
                        ((unsigned int)__builtin_bit_cast(unsigned short, hbl) << 16);
      const int coff = wrow * HID + cb + wpair * 2;
      __hip_atomic_store((unsigned int*)(phi + coff), hw, __ATOMIC_RELAXED, __HIP_MEMORY_SCOPE_AGENT);
      __hip_atomic_store((unsigned int*)(plo + coff), lw, __ATOMIC_RELAXED, __HIP_MEMORY_SCOPE_AGENT);
    }
    RELEASE_DRAIN();   // h stores ack'd at coherence point before the count bump
  };

  if (layer == 0) {
    for (int t = 0; t < S_LEN; ++t) {
      if (t && (t & fimask) == 0)
        __builtin_amdgcn_fence(__ATOMIC_ACQUIRE, "agent");  // slot-reuse invalidate (every W/2)
      f32x4 acc = {0.f, 0.f, 0.f, 0.f};
      // x part first: independent of the recurrence
      const float* xr = x + ((size_t)brow * S_LEN + t) * IN_D + q8;
      #pragma unroll
      for (int kb = 0; kb < 2; ++kb) {
        f32x4 xa = *(const f32x4*)(xr + kb * 32);
        f32x4 xb = *(const f32x4*)(xr + kb * 32 + 4);
        f16x8 a = { (f16)xa[0], (f16)xa[1], (f16)xa[2], (f16)xa[3],
                    (f16)xb[0], (f16)xb[1], (f16)xb[2], (f16)xb[3] };
        f16x8 bf = *(const f16x8*)(w0l + (tile * 16 + fm) * KP0 + kb * 32 + q8);
        acc = MFMA(a, bf, acc);
      }
      if (t) {
        wait4(f0cnt, t - 1, budget);                            // h0(t-1) ready
        if (t > slack) wait4(f1cnt, t - slack - 1, budget);     // window back-pressure
        const f16* hpi = slotp(0, t - 1, 0) + fm * HID + q8;
        const f16* hpl = slotp(0, t - 1, 1) + fm * HID + q8;
        // batch all 32 loads -> one latency exposure
        f16x8 ah[16], al[16];
        #pragma unroll
        for (int kb = 0; kb < 16; ++kb) {
          ah[kb] = *(const f16x8*)(hpi + kb * 32);
          al[kb] = *(const f16x8*)(hpl + kb * 32);
        }
        // independent hi/lo chains (depth 16 each)
        f32x4 acl = {0.f, 0.f, 0.f, 0.f};
        #pragma unroll
        for (int kb = 0; kb < 16; ++kb) {
          f16x8 bf = *(const f16x8*)(w0l + (tile * 16 + fm) * KP0 + IN_D + kb * 32 + q8);
          acc = MFMA(ah[kb], bf, acc);
          acl = MFMA(al[kb], bf, acl);
        }
        acc = acc + acl;
      }
      do_epilogue(acc, t);
      if (lane == 0) atomicAdd(f0cnt + word * 512 + t, 1u);     // device-scope (G12)
    }
  } else {
    for (int t = 0; t < S_LEN; ++t) {
      if (t && (t & fimask) == 0)
        __builtin_amdgcn_fence(__ATOMIC_ACQUIRE, "agent");
      f32x4 acc = {0.f, 0.f, 0.f, 0.f};
      f32x4 acl = {0.f, 0.f, 0.f, 0.f};
      wait4(f0cnt, t, budget);                                  // h0(t) ready
      {
        const f16* h0i = slotp(0, t, 0) + fm * HID + q8;
        const f16* h0l = slotp(0, t, 1) + fm * HID + q8;
        f16x8 ah[16], al[16];
        #pragma unroll
        for (int kb = 0; kb < 16; ++kb) {
          ah[kb] = *(const f16x8*)(h0i + kb * 32);
          al[kb] = *(const f16x8*)(h0l + kb * 32);
        }
        #pragma unroll
        for (int kb = 0; kb < 16; ++kb) {
          f16x8 bf = *(const f16x8*)(w1l + (tile * 16 + fm) * KP1 + kb * 32 + q8);
          acc = MFMA(ah[kb], bf, acc);
          acl = MFMA(al[kb], bf, acl);
        }
      }
      if (t) {
        wait4(f1cnt, t - 1, budget);                            // h1(t-1) ready (peers)
        const f16* h1i = slotp(1, t - 1, 0) + fm * HID + q8;
        const f16* h1l = slotp(1, t - 1, 1) + fm * HID + q8;
        f16x8 ah[16], al[16];
        #pragma unroll
        for (int kb = 0; kb < 16; ++kb) {
          ah[kb] = *(const f16x8*)(h1i + kb * 32);
          al[kb] = *(const f16x8*)(h1l + kb * 32);
        }
        #pragma unroll
        for (int kb = 0; kb < 16; ++kb) {
          f16x8 bf = *(const f16x8*)(w1l + (tile * 16 + fm) * KP1 + HID + kb * 32 + q8);
          acc = MFMA(ah[kb], bf, acc);
          acl = MFMA(al[kb], bf, acl);
        }
      }
      acc = acc + acl;
      do_epilogue(acc, t);
      if (lane == 0) atomicAdd(f1cnt + word * 512 + t, 1u);
    }
  }

  // ---- output head: WG0 of each cluster reads h1(511) ----
  if (wg == 0) {
    wait4(f1cnt, S_LEN - 1, budget);
    __builtin_amdgcn_fence(__ATOMIC_ACQUIRE, "agent");
    const f16* h1i = slotp(1, S_LEN - 1, 0);
    const f16* h1l = slotp(1, S_LEN - 1, 1);
    #pragma unroll
    for (int rr = 0; rr < 4; ++rr) {
      const int r = wave * 4 + rr;
      float sum = 0.f;
      for (int k = lane; k < HID; k += 64) {
        float hv = (float)h1i[r * HID + k] + (float)h1l[r * HID + k];
        sum += hv * Wfc[k];
      }
      #pragma unroll
      for (int off = 32; off > 0; off >>= 1)
        sum += __shfl_down(sum, off, 64);
      if (lane == 0) out[cl * BPC + r] = sum + bfc[0];
    }
  }
}

extern "C" void kernel_launch(void* const* d_in, const int* in_sizes, int n_in,
                              void* d_out, int out_size, void* d_ws, size_t ws_size,
                              hipStream_t stream) {
  const float* x   = (const float*)d_in[0];
  const float* W0  = (const float*)d_in[1];
  const float* b0  = (const float*)d_in[2];
  const float* W1  = (const float*)d_in[3];
  const float* b1  = (const float*)d_in[4];
  const float* Wfc = (const float*)d_in[5];
  const float* bfc = (const float*)d_in[6];
  float* out = (float*)d_out;
  unsigned char* ws = (unsigned char*)d_ws;

  (void)in_sizes; (void)n_in; (void)out_size;

  // window size from available workspace (cap 64 slots = 16.8 MB)
  int Wn = 2;
  while (Wn < 64 &&
         WS_FLAG_BYTES + (size_t)(Wn * 2) * (CLUSTERS * 2 * SLOT_BYTES) <= ws_size)
    Wn *= 2;
  int wmask  = Wn - 1;
  int fimask = (Wn >= 4) ? (Wn / 2 - 1) : 0;  // acquire-fence every Wn/2 steps
  int slack  = Wn - 2;

  hipFuncSetAttribute((const void*)lstm_persist,
                      hipFuncAttributeMaxDynamicSharedMemorySize, LDS_TOTAL);

  // zero the counter region each call (h slots are written before read)
  hipMemsetAsync(ws, 0, WS_FLAG_BYTES, stream);

  void* args[] = { &x, &W0, &b0, &W1, &b1, &Wfc, &bfc, &out, &ws,
                   &Wn, &wmask, &fimask, &slack };
  hipLaunchCooperativeKernel((void*)lstm_persist, dim3(NBLOCKS), dim3(NTHREADS),
                             args, LDS_TOTAL, stream);
}

// Round 12
// 4598.912 us; speedup vs baseline: 1.3837x; 1.0251x over previous
//
#include <hip/hip_runtime.h>

// ---------------- problem constants ----------------
#define S_LEN 512
#define HID   512
#define IN_D  64
#define GATES 2048            // 4*HID
#define K0    576             // IN_D + HID
#define K1    1024            // HID + HID
#define KP0   578             // padded LDS stride (dwords % 32 == 1 -> conflict-free B reads)
#define KP1   1026
#define CLUSTERS 4
#define WGS   64              // workgroups per cluster
#define BPC   16              // batch rows per cluster
#define NBLOCKS 256
#define NTHREADS 256
#define NEED_W 32u            // producers per counter word (128 waves / 4 words)

typedef _Float16 f16;
typedef _Float16 f16x8 __attribute__((ext_vector_type(8)));
typedef float    f32x4 __attribute__((ext_vector_type(4)));

// ---------------- LDS layout (dynamic) ----------------
#define LDS_W0_OFF  0
#define LDS_W1_OFF  (32 * KP0 * 2)                    // 36992
#define LDS_STG_OFF (LDS_W1_OFF + 32 * KP1 * 2)      // 102656
#define LDS_TOTAL   (LDS_STG_OFF + 4 * 16 * 17 * 4)  // 107008 bytes

// ---------------- workspace layout ----------------
// [0 .. 64K): per-cluster 4-LINE step counters (round-11, proven −9%).
//   cluster c at ws + c*16384:
//     f0cnt: 4 word-arrays u32[512], word w at +w*2048   (8 KB total)
//     f1cnt: same, at +8192.
//   Producer wave wid bumps word (wid & 3); ready <=> all 4 words == 32.
// [64K .. ): versioned h slots:
//   (cl*2+layer)*Wn + (t & wmask), 32 KB each (hi plane 16 KB, lo plane 16 KB)
// ROUND-12 DELTA: L1 cross-iteration h0 prefetch (the only prefetchable edge:
//   L0 runs ahead, so f0cnt[t+1] is normally satisfied when L1 finishes t;
//   issuing h0 loads at the END of step t overlaps their latency with the
//   publish drain and the peers' f1 flag propagation). Registers are immune
//   to slot overwrite; load completes before L0 can reuse the address (L0's
//   back-pressure needs f1[t+1] from THIS wave); fence cadence unaffected
//   (prefetch shifts reads earlier = more reuse margin).
#define WS_FLAG_BYTES 65536
#define SLOT_BYTES    32768

#define RELEASE_DRAIN() asm volatile("s_waitcnt vmcnt(0) lgkmcnt(0)" ::: "memory")
#define MFMA(a,b,c) __builtin_amdgcn_mfma_f32_16x16x32_f16((a),(b),(c),0,0,0)

__device__ __forceinline__ float sigf(float v) {
  v = fminf(fmaxf(v, -30.f), 30.f);
  return 1.f / (1.f + __expf(-v));
}
__device__ __forceinline__ float tanh_f(float v) {
  v = fminf(fmaxf(v, -15.f), 15.f);
  float e = __expf(2.f * v);
  return (e - 1.f) / (e + 1.f);
}

// poll one step's 4 spread counter words (4 concurrent loads, 4 lines).
// budget bail-out: protocol failure finishes fast with wrong numbers (loud).
__device__ __forceinline__ void wait4(const unsigned* arr, int t, int& budget) {
  const unsigned* p0 = arr + t;
  const unsigned* p1 = arr + 512 + t;
  const unsigned* p2 = arr + 1024 + t;
  const unsigned* p3 = arr + 1536 + t;
  for (;;) {
    unsigned a = __hip_atomic_load(p0, __ATOMIC_RELAXED, __HIP_MEMORY_SCOPE_AGENT);
    unsigned b = __hip_atomic_load(p1, __ATOMIC_RELAXED, __HIP_MEMORY_SCOPE_AGENT);
    unsigned c = __hip_atomic_load(p2, __ATOMIC_RELAXED, __HIP_MEMORY_SCOPE_AGENT);
    unsigned d = __hip_atomic_load(p3, __ATOMIC_RELAXED, __HIP_MEMORY_SCOPE_AGENT);
    if (a >= NEED_W && b >= NEED_W && c >= NEED_W && d >= NEED_W) break;
    if (--budget < 0) break;
    __builtin_amdgcn_s_sleep(1);
  }
  asm volatile("" ::: "memory");   // compiler acquire: keep data loads after the poll
}

extern "C" __global__ void __launch_bounds__(NTHREADS, 1)
lstm_persist(const float* __restrict__ x,  const float* __restrict__ W0,
             const float* __restrict__ b0, const float* __restrict__ W1,
             const float* __restrict__ b1, const float* __restrict__ Wfc,
             const float* __restrict__ bfc, float* __restrict__ out,
             unsigned char* __restrict__ ws, int Wn, int wmask, int fimask, int slack)
{
  extern __shared__ char lds[];
  f16*   w0l     = (f16*)(lds + LDS_W0_OFF);
  f16*   w1l     = (f16*)(lds + LDS_W1_OFF);
  float* stgbase = (float*)(lds + LDS_STG_OFF);

  const int tid   = threadIdx.x;
  const int wg    = blockIdx.x & (WGS - 1);
  const int cl    = blockIdx.x / WGS;
  const int wave  = tid >> 6;
  const int lane  = tid & 63;
  const int hbase = wg * 8;

  // ---- one-time: gather + transpose this WG's weight columns into LDS (fp16) ----
  {
    const int nl = tid & 31;
    const int wtile = nl >> 4, wi = nl & 15, g = wi >> 2, jj = wi & 3;
    const int col = g * HID + hbase + wtile * 4 + jj;
    for (int k = tid >> 5; k < K0; k += 8)
      w0l[nl * KP0 + k] = (f16)W0[(size_t)k * GATES + col];
    for (int k = tid >> 5; k < K1; k += 8)
      w1l[nl * KP1 + k] = (f16)W1[(size_t)k * GATES + col];
  }
  __syncthreads();   // last block-wide sync; waves run independently below

  // ---- per-wave constants ----
  const int layer = wave >> 1;
  const int tile  = wave & 1;
  const int cb    = hbase + tile * 4;
  const int erow  = lane >> 2;
  const int ehc   = lane & 3;
  const int hcol  = cb + ehc;
  const float* bsrc = layer ? b1 : b0;
  const float bg0 = bsrc[0 * HID + hcol];
  const float bg1 = bsrc[1 * HID + hcol];
  const float bg2 = bsrc[2 * HID + hcol];
  const float bg3 = bsrc[3 * HID + hcol];
  float cstate = 0.f;
  float* stg = stgbase + wave * (16 * 17);

  const int fm  = lane & 15;
  const int q8  = (lane >> 4) * 8;
  const int brow = cl * BPC + fm;
  const int wid  = wg * 2 + tile;          // producer wave id 0..127
  const int word = wid & 3;                // which spread line this wave bumps

  unsigned char* hby = ws + WS_FLAG_BYTES;
  unsigned int* f0cnt = (unsigned int*)(ws + (size_t)cl * 16384);
  unsigned int* f1cnt = (unsigned int*)(ws + (size_t)cl * 16384 + 8192);
  int budget = 1 << 20;

  auto slotp = [&](int lyr, int t, int hl) -> f16* {
    return (f16*)(hby + ((size_t)((cl * 2 + lyr) * Wn + (t & wmask)) << 15) + (hl << 14));
  };

  // epilogue: acc -> gates -> (h, cstate) -> versioned slot store
  auto do_epilogue = [&](f32x4 acc, int t) {
    #pragma unroll
    for (int r = 0; r < 4; ++r)
      stg[((lane >> 4) * 4 + r) * 17 + fm] = acc[r];
    float iv = stg[erow * 17 + 0 + ehc]  + bg0;
    float fv = stg[erow * 17 + 4 + ehc]  + bg1;
    float gv = stg[erow * 17 + 8 + ehc]  + bg2;
    float ov = stg[erow * 17 + 12 + ehc] + bg3;
    float ig = sigf(iv), fg = sigf(fv), gg = tanh_f(gv), og = sigf(ov);
    cstate = fg * cstate + ig * gg;
    float h = og * tanh_f(cstate);

    const int src0 = fm * 4 + ((lane >> 4) & 1) * 2;
    float ha = __shfl(h, src0, 64);
    float hb = __shfl(h, src0 + 1, 64);
    if (lane < 32) {
      const int wrow = lane & 15, wpair = lane >> 4;
      f16* phi = slotp(layer, t, 0);
      f16* plo = slotp(layer, t, 1);
      f16 hah = (f16)ha; f16 hal = (f16)(ha - (float)hah);
      f16 hbh = (f16)hb; f16 hbl = (f16)(hb - (float)hbh);
      unsigned int hw = (unsigned int)__builtin_bit_cast(unsigned short, hah) |
                        ((unsigned int)__builtin_bit_cast(unsigned short, hbh) << 16);
      unsigned int lw = (unsigned int)__builtin_bit_cast(unsigned short, hal) |
                        ((unsigned int)__builtin_bit_cast(unsigned short, hbl) << 16);
      const int coff = wrow * HID + cb + wpair * 2;
      __hip_atomic_store((unsigned int*)(phi + coff), hw, __ATOMIC_RELAXED, __HIP_MEMORY_SCOPE_AGENT);
      __hip_atomic_store((unsigned int*)(plo + coff), lw, __ATOMIC_RELAXED, __HIP_MEMORY_SCOPE_AGENT);
    }
    RELEASE_DRAIN();   // h stores ack'd at coherence point before the count bump
  };

  if (layer == 0) {
    for (int t = 0; t < S_LEN; ++t) {
      if (t && (t & fimask) == 0)
        __builtin_amdgcn_fence(__ATOMIC_ACQUIRE, "agent");  // slot-reuse invalidate (every W/2)
      f32x4 acc = {0.f, 0.f, 0.f, 0.f};
      // x part first: independent of the recurrence
      const float* xr = x + ((size_t)brow * S_LEN + t) * IN_D + q8;
      #pragma unroll
      for (int kb = 0; kb < 2; ++kb) {
        f32x4 xa = *(const f32x4*)(xr + kb * 32);
        f32x4 xb = *(const f32x4*)(xr + kb * 32 + 4);
        f16x8 a = { (f16)xa[0], (f16)xa[1], (f16)xa[2], (f16)xa[3],
                    (f16)xb[0], (f16)xb[1], (f16)xb[2], (f16)xb[3] };
        f16x8 bf = *(const f16x8*)(w0l + (tile * 16 + fm) * KP0 + kb * 32 + q8);
        acc = MFMA(a, bf, acc);
      }
      if (t) {
        wait4(f0cnt, t - 1, budget);                            // h0(t-1) ready
        if (t > slack) wait4(f1cnt, t - slack - 1, budget);     // window back-pressure
        const f16* hpi = slotp(0, t - 1, 0) + fm * HID + q8;
        const f16* hpl = slotp(0, t - 1, 1) + fm * HID + q8;
        // batch all 32 loads -> one latency exposure
        f16x8 ah[16], al[16];
        #pragma unroll
        for (int kb = 0; kb < 16; ++kb) {
          ah[kb] = *(const f16x8*)(hpi + kb * 32);
          al[kb] = *(const f16x8*)(hpl + kb * 32);
        }
        // independent hi/lo chains (depth 16 each)
        f32x4 acl = {0.f, 0.f, 0.f, 0.f};
        #pragma unroll
        for (int kb = 0; kb < 16; ++kb) {
          f16x8 bf = *(const f16x8*)(w0l + (tile * 16 + fm) * KP0 + IN_D + kb * 32 + q8);
          acc = MFMA(ah[kb], bf, acc);
          acl = MFMA(al[kb], bf, acl);
        }
        acc = acc + acl;
      }
      do_epilogue(acc, t);
      if (lane == 0) atomicAdd(f0cnt + word * 512 + t, 1u);     // device-scope (G12)
    }
  } else {
    // ---- ROUND-12 DELTA: persistent-register h0 pipeline ----
    f16x8 ah0[16], al0[16];
    wait4(f0cnt, 0, budget);                                    // h0(0) ready
    {
      const f16* h0i = slotp(0, 0, 0) + fm * HID + q8;
      const f16* h0l = slotp(0, 0, 1) + fm * HID + q8;
      #pragma unroll
      for (int kb = 0; kb < 16; ++kb) {
        ah0[kb] = *(const f16x8*)(h0i + kb * 32);
        al0[kb] = *(const f16x8*)(h0l + kb * 32);
      }
    }
    for (int t = 0; t < S_LEN; ++t) {
      if (t && (t & fimask) == 0)
        __builtin_amdgcn_fence(__ATOMIC_ACQUIRE, "agent");      // slot-reuse invalidate
      // h0 part from prefetched registers (loads issued last iteration)
      f32x4 acc = {0.f, 0.f, 0.f, 0.f};
      f32x4 acl = {0.f, 0.f, 0.f, 0.f};
      #pragma unroll
      for (int kb = 0; kb < 16; ++kb) {
        f16x8 bf = *(const f16x8*)(w1l + (tile * 16 + fm) * KP1 + kb * 32 + q8);
        acc = MFMA(ah0[kb], bf, acc);
        acl = MFMA(al0[kb], bf, acl);
      }
      if (t) {
        wait4(f1cnt, t - 1, budget);                            // h1(t-1) ready (peers)
        const f16* h1i = slotp(1, t - 1, 0) + fm * HID + q8;
        const f16* h1l = slotp(1, t - 1, 1) + fm * HID + q8;
        f16x8 ah[16], al[16];
        #pragma unroll
        for (int kb = 0; kb < 16; ++kb) {
          ah[kb] = *(const f16x8*)(h1i + kb * 32);
          al[kb] = *(const f16x8*)(h1l + kb * 32);
        }
        #pragma unroll
        for (int kb = 0; kb < 16; ++kb) {
          f16x8 bf = *(const f16x8*)(w1l + (tile * 16 + fm) * KP1 + HID + kb * 32 + q8);
          acc = MFMA(ah[kb], bf, acc);
          acl = MFMA(al[kb], bf, acl);
        }
      }
      acc = acc + acl;
      do_epilogue(acc, t);
      if (lane == 0) atomicAdd(f1cnt + word * 512 + t, 1u);
      // prefetch h0(t+1): issued after publish; latency overlaps drain + the
      // peers' f1 propagation. wait4's compiler-barrier orders loads after poll.
      if (t + 1 < S_LEN) {
        wait4(f0cnt, t + 1, budget);                            // usually no spin
        const f16* h0i = slotp(0, t + 1, 0) + fm * HID + q8;
        const f16* h0l = slotp(0, t + 1, 1) + fm * HID + q8;
        #pragma unroll
        for (int kb = 0; kb < 16; ++kb) {
          ah0[kb] = *(const f16x8*)(h0i + kb * 32);
          al0[kb] = *(const f16x8*)(h0l + kb * 32);
        }
      }
    }
  }

  // ---- output head: WG0 of each cluster reads h1(511) ----
  if (wg == 0) {
    wait4(f1cnt, S_LEN - 1, budget);
    __builtin_amdgcn_fence(__ATOMIC_ACQUIRE, "agent");
    const f16* h1i = slotp(1, S_LEN - 1, 0);
    const f16* h1l = slotp(1, S_LEN - 1, 1);
    #pragma unroll
    for (int rr = 0; rr < 4; ++rr) {
      const int r = wave * 4 + rr;
      float sum = 0.f;
      for (int k = lane; k < HID; k += 64) {
        float hv = (float)h1i[r * HID + k] + (float)h1l[r * HID + k];
        sum += hv * Wfc[k];
      }
      #pragma unroll
      for (int off = 32; off > 0; off >>= 1)
        sum += __shfl_down(sum, off, 64);
      if (lane == 0) out[cl * BPC + r] = sum + bfc[0];
    }
  }
}

extern "C" void kernel_launch(void* const* d_in, const int* in_sizes, int n_in,
                              void* d_out, int out_size, void* d_ws, size_t ws_size,
                              hipStream_t stream) {
  const float* x   = (const float*)d_in[0];
  const float* W0  = (const float*)d_in[1];
  const float* b0  = (const float*)d_in[2];
  const float* W1  = (const float*)d_in[3];
  const float* b1  = (const float*)d_in[4];
  const float* Wfc = (const float*)d_in[5];
  const float* bfc = (const float*)d_in[6];
  float* out = (float*)d_out;
  unsigned char* ws = (unsigned char*)d_ws;

  (void)in_sizes; (void)n_in; (void)out_size;

  // window size from available workspace (cap 64 slots = 16.8 MB)
  int Wn = 2;
  while (Wn < 64 &&
         WS_FLAG_BYTES + (size_t)(Wn * 2) * (CLUSTERS * 2 * SLOT_BYTES) <= ws_size)
    Wn *= 2;
  int wmask  = Wn - 1;
  int fimask = (Wn >= 4) ? (Wn / 2 - 1) : 0;  // acquire-fence every Wn/2 steps
  int slack  = Wn - 2;

  hipFuncSetAttribute((const void*)lstm_persist,
                      hipFuncAttributeMaxDynamicSharedMemorySize, LDS_TOTAL);

  // zero the counter region each call (h slots are written before read)
  hipMemsetAsync(ws, 0, WS_FLAG_BYTES, stream);

  void* args[] = { &x, &W0, &b0, &W1, &b1, &Wfc, &bfc, &out, &ws,
                   &Wn, &wmask, &fimask, &slack };
  hipLaunchCooperativeKernel((void*)lstm_persist, dim3(NBLOCKS), dim3(NTHREADS),
                             args, LDS_TOTAL, stream);
}

// Round 13
// 4593.097 us; speedup vs baseline: 1.3855x; 1.0013x over previous
//
#include <hip/hip_runtime.h>

// ---------------- problem constants ----------------
#define S_LEN 512
#define HID   512
#define IN_D  64
#define GATES 2048            // 4*HID
#define K0    576             // IN_D + HID
#define K1    1024            // HID + HID
#define KP0   578             // padded LDS stride (dwords % 32 == 1 -> conflict-free B reads)
#define KP1   1026
#define CLUSTERS 4
#define WGS   64              // workgroups per cluster
#define BPC   16              // batch rows per cluster
#define NBLOCKS 256
#define NTHREADS 256
#define NEED_W 32u            // producers per counter word (128 waves / 4 words)

typedef _Float16 f16;
typedef _Float16 f16x8 __attribute__((ext_vector_type(8)));
typedef float    f32x4 __attribute__((ext_vector_type(4)));

// ---------------- LDS layout (dynamic) ----------------
#define LDS_W0_OFF  0
#define LDS_W1_OFF  (32 * KP0 * 2)                    // 36992
#define LDS_STG_OFF (LDS_W1_OFF + 32 * KP1 * 2)      // 102656
#define LDS_TOTAL   (LDS_STG_OFF + 4 * 16 * 17 * 4)  // 107008 bytes

// ---------------- workspace layout ----------------
// [0 .. 64K): per-cluster 4-LINE step counters (round-11, proven −9%).
//   cluster c at ws + c*16384:
//     f0cnt: 4 word-arrays u32[512], word w at +w*2048   (8 KB total)
//     f1cnt: same, at +8192.
//   Producer wave wid bumps word (wid & 3); ready <=> all 4 words == 32.
// [64K .. ): versioned h slots:
//   (cl*2+layer)*Wn + (t & wmask), 32 KB each (hi plane 16 KB, lo plane 16 KB)
// ROUND-13 DELTA: L1 h0 prefetch made un-sinkable. Round 12 used plain loads;
//   VGPR_Count=100 (<128 needed for the arrays) proved the compiler SANK them
//   back to the consume site, nullifying the prefetch. Now the 32 loads are
//   issued via asm volatile global_load_dwordx4 (no internal waitcnt) at the
//   loop TAIL (after publish); a manual s_waitcnt vmcnt(0) + sched_barrier(0)
//   at the loop TOP completes them (rule-18 fence: compiler doesn't track
//   asm-issued loads, and MFMAs could otherwise schedule before the waitcnt).
//   vmcnt audit: at loop-top the ONLY outstanding VMEM is these 32 loads.
#define WS_FLAG_BYTES 65536
#define SLOT_BYTES    32768

#define RELEASE_DRAIN() asm volatile("s_waitcnt vmcnt(0) lgkmcnt(0)" ::: "memory")
#define MFMA(a,b,c) __builtin_amdgcn_mfma_f32_16x16x32_f16((a),(b),(c),0,0,0)

__device__ __forceinline__ float sigf(float v) {
  v = fminf(fmaxf(v, -30.f), 30.f);
  return 1.f / (1.f + __expf(-v));
}
__device__ __forceinline__ float tanh_f(float v) {
  v = fminf(fmaxf(v, -15.f), 15.f);
  float e = __expf(2.f * v);
  return (e - 1.f) / (e + 1.f);
}

// async load issue: position pinned by volatile, NO waitcnt inside — the
// result registers are NOT ready until the manual vmcnt(0) at the consume site.
__device__ __forceinline__ void gload_async(f16x8& r, const f16* p) {
  asm volatile("global_load_dwordx4 %0, %1, off" : "=v"(r) : "v"(p) : "memory");
}

// poll one step's 4 spread counter words (4 concurrent loads, 4 lines).
// budget bail-out: protocol failure finishes fast with wrong numbers (loud).
__device__ __forceinline__ void wait4(const unsigned* arr, int t, int& budget) {
  const unsigned* p0 = arr + t;
  const unsigned* p1 = arr + 512 + t;
  const unsigned* p2 = arr + 1024 + t;
  const unsigned* p3 = arr + 1536 + t;
  for (;;) {
    unsigned a = __hip_atomic_load(p0, __ATOMIC_RELAXED, __HIP_MEMORY_SCOPE_AGENT);
    unsigned b = __hip_atomic_load(p1, __ATOMIC_RELAXED, __HIP_MEMORY_SCOPE_AGENT);
    unsigned c = __hip_atomic_load(p2, __ATOMIC_RELAXED, __HIP_MEMORY_SCOPE_AGENT);
    unsigned d = __hip_atomic_load(p3, __ATOMIC_RELAXED, __HIP_MEMORY_SCOPE_AGENT);
    if (a >= NEED_W && b >= NEED_W && c >= NEED_W && d >= NEED_W) break;
    if (--budget < 0) break;
    __builtin_amdgcn_s_sleep(1);
  }
  asm volatile("" ::: "memory");   // compiler acquire: keep data loads after the poll
}

extern "C" __global__ void __launch_bounds__(NTHREADS, 1)
lstm_persist(const float* __restrict__ x,  const float* __restrict__ W0,
             const float* __restrict__ b0, const float* __restrict__ W1,
             const float* __restrict__ b1, const float* __restrict__ Wfc,
             const float* __restrict__ bfc, float* __restrict__ out,
             unsigned char* __restrict__ ws, int Wn, int wmask, int fimask, int slack)
{
  extern __shared__ char lds[];
  f16*   w0l     = (f16*)(lds + LDS_W0_OFF);
  f16*   w1l     = (f16*)(lds + LDS_W1_OFF);
  float* stgbase = (float*)(lds + LDS_STG_OFF);

  const int tid   = threadIdx.x;
  const int wg    = blockIdx.x & (WGS - 1);
  const int cl    = blockIdx.x / WGS;
  const int wave  = tid >> 6;
  const int lane  = tid & 63;
  const int hbase = wg * 8;

  // ---- one-time: gather + transpose this WG's weight columns into LDS (fp16) ----
  {
    const int nl = tid & 31;
    const int wtile = nl >> 4, wi = nl & 15, g = wi >> 2, jj = wi & 3;
    const int col = g * HID + hbase + wtile * 4 + jj;
    for (int k = tid >> 5; k < K0; k += 8)
      w0l[nl * KP0 + k] = (f16)W0[(size_t)k * GATES + col];
    for (int k = tid >> 5; k < K1; k += 8)
      w1l[nl * KP1 + k] = (f16)W1[(size_t)k * GATES + col];
  }
  __syncthreads();   // last block-wide sync; waves run independently below

  // ---- per-wave constants ----
  const int layer = wave >> 1;
  const int tile  = wave & 1;
  const int cb    = hbase + tile * 4;
  const int erow  = lane >> 2;
  const int ehc   = lane & 3;
  const int hcol  = cb + ehc;
  const float* bsrc = layer ? b1 : b0;
  const float bg0 = bsrc[0 * HID + hcol];
  const float bg1 = bsrc[1 * HID + hcol];
  const float bg2 = bsrc[2 * HID + hcol];
  const float bg3 = bsrc[3 * HID + hcol];
  float cstate = 0.f;
  float* stg = stgbase + wave * (16 * 17);

  const int fm  = lane & 15;
  const int q8  = (lane >> 4) * 8;
  const int brow = cl * BPC + fm;
  const int wid  = wg * 2 + tile;          // producer wave id 0..127
  const int word = wid & 3;                // which spread line this wave bumps

  unsigned char* hby = ws + WS_FLAG_BYTES;
  unsigned int* f0cnt = (unsigned int*)(ws + (size_t)cl * 16384);
  unsigned int* f1cnt = (unsigned int*)(ws + (size_t)cl * 16384 + 8192);
  int budget = 1 << 20;

  auto slotp = [&](int lyr, int t, int hl) -> f16* {
    return (f16*)(hby + ((size_t)((cl * 2 + lyr) * Wn + (t & wmask)) << 15) + (hl << 14));
  };

  // epilogue: acc -> gates -> (h, cstate) -> versioned slot store
  auto do_epilogue = [&](f32x4 acc, int t) {
    #pragma unroll
    for (int r = 0; r < 4; ++r)
      stg[((lane >> 4) * 4 + r) * 17 + fm] = acc[r];
    float iv = stg[erow * 17 + 0 + ehc]  + bg0;
    float fv = stg[erow * 17 + 4 + ehc]  + bg1;
    float gv = stg[erow * 17 + 8 + ehc]  + bg2;
    float ov = stg[erow * 17 + 12 + ehc] + bg3;
    float ig = sigf(iv), fg = sigf(fv), gg = tanh_f(gv), og = sigf(ov);
    cstate = fg * cstate + ig * gg;
    float h = og * tanh_f(cstate);

    const int src0 = fm * 4 + ((lane >> 4) & 1) * 2;
    float ha = __shfl(h, src0, 64);
    float hb = __shfl(h, src0 + 1, 64);
    if (lane < 32) {
      const int wrow = lane & 15, wpair = lane >> 4;
      f16* phi = slotp(layer, t, 0);
      f16* plo = slotp(layer, t, 1);
      f16 hah = (f16)ha; f16 hal = (f16)(ha - (float)hah);
      f16 hbh = (f16)hb; f16 hbl = (f16)(hb - (float)hbh);
      unsigned int hw = (unsigned int)__builtin_bit_cast(unsigned short, hah) |
                        ((unsigned int)__builtin_bit_cast(unsigned short, hbh) << 16);
      unsigned int lw = (unsigned int)__builtin_bit_cast(unsigned short, hal) |
                        ((unsigned int)__builtin_bit_cast(unsigned short, hbl) << 16);
      const int coff = wrow * HID + cb + wpair * 2;
      __hip_atomic_store((unsigned int*)(phi + coff), hw, __ATOMIC_RELAXED, __HIP_MEMORY_SCOPE_AGENT);
      __hip_atomic_store((unsigned int*)(plo + coff), lw, __ATOMIC_RELAXED, __HIP_MEMORY_SCOPE_AGENT);
    }
    RELEASE_DRAIN();   // h stores ack'd at coherence point before the count bump
  };

  if (layer == 0) {
    for (int t = 0; t < S_LEN; ++t) {
      if (t && (t & fimask) == 0)
        __builtin_amdgcn_fence(__ATOMIC_ACQUIRE, "agent");  // slot-reuse invalidate (every W/2)
      f32x4 acc = {0.f, 0.f, 0.f, 0.f};
      // x part first: independent of the recurrence
      const float* xr = x + ((size_t)brow * S_LEN + t) * IN_D + q8;
      #pragma unroll
      for (int kb = 0; kb < 2; ++kb) {
        f32x4 xa = *(const f32x4*)(xr + kb * 32);
        f32x4 xb = *(const f32x4*)(xr + kb * 32 + 4);
        f16x8 a = { (f16)xa[0], (f16)xa[1], (f16)xa[2], (f16)xa[3],
                    (f16)xb[0], (f16)xb[1], (f16)xb[2], (f16)xb[3] };
        f16x8 bf = *(const f16x8*)(w0l + (tile * 16 + fm) * KP0 + kb * 32 + q8);
        acc = MFMA(a, bf, acc);
      }
      if (t) {
        wait4(f0cnt, t - 1, budget);                            // h0(t-1) ready
        if (t > slack) wait4(f1cnt, t - slack - 1, budget);     // window back-pressure
        const f16* hpi = slotp(0, t - 1, 0) + fm * HID + q8;
        const f16* hpl = slotp(0, t - 1, 1) + fm * HID + q8;
        // batch all 32 loads -> one latency exposure
        f16x8 ah[16], al[16];
        #pragma unroll
        for (int kb = 0; kb < 16; ++kb) {
          ah[kb] = *(const f16x8*)(hpi + kb * 32);
          al[kb] = *(const f16x8*)(hpl + kb * 32);
        }
        // independent hi/lo chains (depth 16 each)
        f32x4 acl = {0.f, 0.f, 0.f, 0.f};
        #pragma unroll
        for (int kb = 0; kb < 16; ++kb) {
          f16x8 bf = *(const f16x8*)(w0l + (tile * 16 + fm) * KP0 + IN_D + kb * 32 + q8);
          acc = MFMA(ah[kb], bf, acc);
          acl = MFMA(al[kb], bf, acl);
        }
        acc = acc + acl;
      }
      do_epilogue(acc, t);
      if (lane == 0) atomicAdd(f0cnt + word * 512 + t, 1u);     // device-scope (G12)
    }
  } else {
    // ---- ROUND-13: async-issued persistent-register h0 pipeline ----
    f16x8 ah0[16], al0[16];
    wait4(f0cnt, 0, budget);                                    // h0(0) ready
    {
      const f16* h0i = slotp(0, 0, 0) + fm * HID + q8;
      const f16* h0l = slotp(0, 0, 1) + fm * HID + q8;
      #pragma unroll
      for (int kb = 0; kb < 16; ++kb) {
        gload_async(ah0[kb], h0i + kb * 32);
        gload_async(al0[kb], h0l + kb * 32);
      }
    }
    for (int t = 0; t < S_LEN; ++t) {
      if (t && (t & fimask) == 0)
        __builtin_amdgcn_fence(__ATOMIC_ACQUIRE, "agent");      // slot-reuse invalidate
      // complete the prefetch issued at the previous loop tail; sched_barrier
      // prevents the MFMAs (consumers of asm-produced regs) from being
      // scheduled above the waitcnt (compiler doesn't track asm-issued loads).
      asm volatile("s_waitcnt vmcnt(0)" ::: "memory");
      __builtin_amdgcn_sched_barrier(0);
      // h0 part from prefetched registers
      f32x4 acc = {0.f, 0.f, 0.f, 0.f};
      f32x4 acl = {0.f, 0.f, 0.f, 0.f};
      #pragma unroll
      for (int kb = 0; kb < 16; ++kb) {
        f16x8 bf = *(const f16x8*)(w1l + (tile * 16 + fm) * KP1 + kb * 32 + q8);
        acc = MFMA(ah0[kb], bf, acc);
        acl = MFMA(al0[kb], bf, acl);
      }
      if (t) {
        wait4(f1cnt, t - 1, budget);                            // h1(t-1) ready (peers)
        const f16* h1i = slotp(1, t - 1, 0) + fm * HID + q8;
        const f16* h1l = slotp(1, t - 1, 1) + fm * HID + q8;
        f16x8 ah[16], al[16];
        #pragma unroll
        for (int kb = 0; kb < 16; ++kb) {
          ah[kb] = *(const f16x8*)(h1i + kb * 32);
          al[kb] = *(const f16x8*)(h1l + kb * 32);
        }
        #pragma unroll
        for (int kb = 0; kb < 16; ++kb) {
          f16x8 bf = *(const f16x8*)(w1l + (tile * 16 + fm) * KP1 + HID + kb * 32 + q8);
          acc = MFMA(ah[kb], bf, acc);
          acl = MFMA(al[kb], bf, acl);
        }
      }
      acc = acc + acl;
      do_epilogue(acc, t);
      if (lane == 0) atomicAdd(f1cnt + word * 512 + t, 1u);
      // issue (not wait) h0(t+1) prefetch: latency flies across the loop edge,
      // overlapping the peers' drains + f1 propagation + our next-step detect.
      if (t + 1 < S_LEN) {
        wait4(f0cnt, t + 1, budget);                            // usually no spin
        const f16* h0i = slotp(0, t + 1, 0) + fm * HID + q8;
        const f16* h0l = slotp(0, t + 1, 1) + fm * HID + q8;
        #pragma unroll
        for (int kb = 0; kb < 16; ++kb) {
          gload_async(ah0[kb], h0i + kb * 32);
          gload_async(al0[kb], h0l + kb * 32);
        }
      }
    }
  }

  // ---- output head: WG0 of each cluster reads h1(511) ----
  if (wg == 0) {
    wait4(f1cnt, S_LEN - 1, budget);
    __builtin_amdgcn_fence(__ATOMIC_ACQUIRE, "agent");
    const f16* h1i = slotp(1, S_LEN - 1, 0);
    const f16* h1l = slotp(1, S_LEN - 1, 1);
    #pragma unroll
    for (int rr = 0; rr < 4; ++rr) {
      const int r = wave * 4 + rr;
      float sum = 0.f;
      for (int k = lane; k < HID; k += 64) {
        float hv = (float)h1i[r * HID + k] + (float)h1l[r * HID + k];
        sum += hv * Wfc[k];
      }
      #pragma unroll
      for (int off = 32; off > 0; off >>= 1)
        sum += __shfl_down(sum, off, 64);
      if (lane == 0) out[cl * BPC + r] = sum + bfc[0];
    }
  }
}

extern "C" void kernel_launch(void* const* d_in, const int* in_sizes, int n_in,
                              void* d_out, int out_size, void* d_ws, size_t ws_size,
                              hipStream_t stream) {
  const float* x   = (const float*)d_in[0];
  const float* W0  = (const float*)d_in[1];
  const float* b0  = (const float*)d_in[2];
  const float* W1  = (const float*)d_in[3];
  const float* b1  = (const float*)d_in[4];
  const float* Wfc = (const float*)d_in[5];
  const float* bfc = (const float*)d_in[6];
  float* out = (float*)d_out;
  unsigned char* ws = (unsigned char*)d_ws;

  (void)in_sizes; (void)n_in; (void)out_size;

  // window size from available workspace (cap 64 slots = 16.8 MB)
  int Wn = 2;
  while (Wn < 64 &&
         WS_FLAG_BYTES + (size_t)(Wn * 2) * (CLUSTERS * 2 * SLOT_BYTES) <= ws_size)
    Wn *= 2;
  int wmask  = Wn - 1;
  int fimask = (Wn >= 4) ? (Wn / 2 - 1) : 0;  // acquire-fence every Wn/2 steps
  int slack  = Wn - 2;

  hipFuncSetAttribute((const void*)lstm_persist,
                      hipFuncAttributeMaxDynamicSharedMemorySize, LDS_TOTAL);

  // zero the counter region each call (h slots are written before read)
  hipMemsetAsync(ws, 0, WS_FLAG_BYTES, stream);

  void* args[] = { &x, &W0, &b0, &W1, &b1, &Wfc, &bfc, &out, &ws,
                   &Wn, &wmask, &fimask, &slack };
  hipLaunchCooperativeKernel((void*)lstm_persist, dim3(NBLOCKS), dim3(NTHREADS),
                             args, LDS_TOTAL, stream);
}